// Round 14
// baseline (682.274 us; speedup 1.0000x reference)
//
#include <hip/hip_runtime.h>
#include <math.h>

#define N 128
#define B 8
#define CI 32
#define CO 32
#define M1 4
#define M2 5
#define IK (CI*CO)       // 1024
#define IKP (IK*M1)      // 4096
#define IKQ (IK*M2)      // 5120
#define TWO_PI_F 6.2831853071795864769f

// 4 v_fma per cmadd, guaranteed
__device__ __forceinline__ float2 cmul(float2 a, float2 b){
    return make_float2(fmaf(a.x,b.x,-(a.y*b.y)), fmaf(a.x,b.y,a.y*b.x));
}
__device__ __forceinline__ float2 cmadd(float2 acc, float2 a, float2 b){
    acc.x = fmaf(a.x, b.x, fmaf(-a.y, b.y, acc.x));
    acc.y = fmaf(a.x, b.y, fmaf( a.y, b.x, acc.y));
    return acc;
}

// A1T[o][ik*M1+p] = 1/(i*2pi*f(o) - wp1[ik,p]); freq-major for contiguous per-o slices
__global__ void k_A1T(const float* wr_, const float* wi_, const float* t_, float2* A1T){
    int idx = blockIdx.x*256 + threadIdx.x;      // [0, N*IKP)
    int o   = idx >> 12;                          // /IKP
    int ikp = idx & (IKP-1);
    float d = t_[1]-t_[0];
    float invnd = 1.0f/((float)N*d);
    int kk = (o < N/2) ? o : o - N;
    float lam = TWO_PI_F * (float)kk * invnd;
    float dr = -wr_[ikp];
    float di = lam - wi_[ikp];
    float inv = 1.0f/(dr*dr + di*di);
    A1T[idx] = make_float2(dr*inv, -di*inv);
}

// A2[ikq][x] natural layout
__global__ void k_A2(const float* wr_, const float* wi_, const float* t_, float2* A2){
    int idx = blockIdx.x*256 + threadIdx.x;      // [0, IKQ*N)
    int ikq = idx >> 7; int xx = idx & (N-1);
    float d = t_[1]-t_[0];
    float invnd = 1.0f/((float)N*d);
    int kk = (xx < N/2) ? xx : xx - N;
    float lam = TWO_PI_F * (float)kk * invnd;
    float dr = -wr_[ikq];
    float di = lam - wi_[ikq];
    float inv = 1.0f/(dr*dr + di*di);
    A2[idx] = make_float2(dr*inv, -di*inv);
}

// E[ikp][y] = exp(wp[ikp] * t[y])
__global__ void k_E(const float* wr_, const float* wi_, const float* t_, float2* E){
    int idx = blockIdx.x*256 + threadIdx.x;
    int ikp = idx >> 7; int y = idx & (N-1);
    float t = t_[y];
    float m = expf(wr_[ikp]*t);
    float s, c; sincosf(wi_[ikp]*t, &s, &c);
    E[idx] = make_float2(m*c, m*s);
}

// W2T[x][ik*M1+p] = sum_q wr[ik,p,q] * A2[ik,q,x]
__global__ void k_W2T(const float* wrr, const float* wri, const float2* A2, float2* W2T){
    int idx = blockIdx.x*256 + threadIdx.x;      // [0, IKP*N)
    int ikp = idx >> 7; int xx = idx & (N-1);
    int ik = ikp >> 2; int p = ikp & 3;
    float2 acc = make_float2(0.f,0.f);
    const float* wr0 = wrr + ik*(M1*M2) + p*M2;
    const float* wi0 = wri + ik*(M1*M2) + p*M2;
    const float2* a2 = A2 + (size_t)ik*(M2*N) + xx;
    #pragma unroll
    for(int q=0;q<M2;q++){
        float2 w = make_float2(wr0[q], wi0[q]);
        acc = cmadd(acc, w, a2[q*N]);
    }
    W2T[(size_t)xx*IKP + ikp] = acc;
}

// ---------- four-step FFT, 128 = 16 x 8 ----------
template<int SIGNPOS, int REALIN, int SCALE>
__global__ void __launch_bounds__(256) k_fft_rows(const void* in_, float2* out){
    const float sgn = SIGNPOS ? 1.0f : -1.0f;
    __shared__ float tre[16*132];
    __shared__ float tim_[16*132];
    __shared__ float zre[16*136];
    __shared__ float zim[16*136];
    int t = threadIdx.x;
    size_t row0 = (size_t)blockIdx.x * 16;

    if(REALIN){
        const float* src = (const float*)in_ + row0*N;
        #pragma unroll
        for(int j=0;j<8;j++){
            int idx = t + 256*j; int r = idx>>7, cl = idx&127;
            tre[r*132+cl] = src[idx];
        }
    } else {
        const float2* src = (const float2*)in_ + row0*N;
        #pragma unroll
        for(int j=0;j<8;j++){
            int idx = t + 256*j; int r = idx>>7, cl = idx&127;
            float2 v = src[idx];
            tre[r*132+cl] = v.x; tim_[r*132+cl] = v.y;
        }
    }
    float t16c[16], t16s[16];
    #pragma unroll
    for(int j=0;j<16;j++){ float s,c; sincosf(sgn*(TWO_PI_F/16.f)*(float)j, &s,&c); t16c[j]=c; t16s[j]=s; }
    __syncthreads();

    int r = t>>4, u = t&15, b = u&7, h = u>>3;
    float xr[16], xi[16];
    #pragma unroll
    for(int a=0;a<16;a++){
        float vr = tre[r*132 + 8*a + b];
        float vi = REALIN ? 0.f : tim_[r*132 + 8*a + b];
        if(h && (a&1)){ vr = -vr; vi = -vi; }
        xr[a]=vr; xi[a]=vi;
    }
    #pragma unroll
    for(int cc=0; cc<8; cc++){
        float yr=0.f, yi=0.f;
        #pragma unroll
        for(int a=0;a<16;a++){
            int j = (a*cc)&15;
            if(REALIN){
                yr = fmaf(xr[a], t16c[j], yr);
                yi = fmaf(xr[a], t16s[j], yi);
            } else {
                yr = fmaf(xr[a], t16c[j], yr); yr = fmaf(-xi[a], t16s[j], yr);
                yi = fmaf(xr[a], t16s[j], yi); yi = fmaf( xi[a], t16c[j], yi);
            }
        }
        int c = 8*h + cc;
        float s,co; sincosf(sgn*(TWO_PI_F/128.f)*(float)(b*c), &s,&co);
        zre[r*136 + b*17 + c] = fmaf(yr,co,-(yi*s));
        zim[r*136 + b*17 + c] = fmaf(yr,s,  yi*co);
    }
    __syncthreads();

    float t8c[8], t8s[8];
    #pragma unroll
    for(int j=0;j<8;j++){ float s,c; sincosf(sgn*(TWO_PI_F/8.f)*(float)j, &s,&c); t8c[j]=c; t8s[j]=s; }
    int r2 = t>>4, c2 = t&15;
    float zr_[8], zi_[8];
    #pragma unroll
    for(int bb=0;bb<8;bb++){ zr_[bb]=zre[r2*136 + bb*17 + c2]; zi_[bb]=zim[r2*136 + bb*17 + c2]; }
    float2* dst = out + (row0 + r2)*N;
    #pragma unroll
    for(int d=0; d<8; d++){
        float Xr=0.f, Xi=0.f;
        #pragma unroll
        for(int bb=0;bb<8;bb++){
            int j=(bb*d)&7;
            Xr = fmaf(zr_[bb], t8c[j], Xr); Xr = fmaf(-zi_[bb], t8s[j], Xr);
            Xi = fmaf(zr_[bb], t8s[j], Xi); Xi = fmaf( zi_[bb], t8c[j], Xi);
        }
        if(SCALE){ Xr *= (1.f/128.f); Xi *= (1.f/128.f); }
        dst[c2 + 16*d] = make_float2(Xr, Xi);
    }
}

template<int SIGNPOS, int REALOUT, int SCALE>
__global__ void __launch_bounds__(256) k_fft_cols(const float2* in, float2* outc, float* outr){
    const float sgn = SIGNPOS ? 1.0f : -1.0f;
    __shared__ float tre[N*17];
    __shared__ float tim_[N*17];
    __shared__ float zre[8*16*17];
    __shared__ float zim[8*16*17];
    int t = threadIdx.x;
    int img = blockIdx.x >> 3; int x0 = (blockIdx.x & 7)*16;
    const float2* src = in + (size_t)img*N*N + x0;
    #pragma unroll
    for(int j=0;j<8;j++){
        int idx = t + 256*j; int y = idx>>4, xc = idx&15;
        float2 v = src[y*N + xc];
        tre[y*17+xc]=v.x; tim_[y*17+xc]=v.y;
    }
    float t16c[16], t16s[16];
    #pragma unroll
    for(int j=0;j<16;j++){ float s,c; sincosf(sgn*(TWO_PI_F/16.f)*(float)j, &s,&c); t16c[j]=c; t16s[j]=s; }
    __syncthreads();

    int xc = t&15, u = t>>4, b = u&7, h = u>>3;
    float xr[16], xi[16];
    #pragma unroll
    for(int a=0;a<16;a++){
        int y = 8*a + b;
        float vr = tre[y*17+xc];
        float vi = tim_[y*17+xc];
        if(h && (a&1)){ vr = -vr; vi = -vi; }
        xr[a]=vr; xi[a]=vi;
    }
    #pragma unroll
    for(int cc=0; cc<8; cc++){
        float yr=0.f, yi=0.f;
        #pragma unroll
        for(int a=0;a<16;a++){
            int j = (a*cc)&15;
            yr = fmaf(xr[a], t16c[j], yr); yr = fmaf(-xi[a], t16s[j], yr);
            yi = fmaf(xr[a], t16s[j], yi); yi = fmaf( xi[a], t16c[j], yi);
        }
        int c = 8*h + cc;
        float s,co; sincosf(sgn*(TWO_PI_F/128.f)*(float)(b*c), &s,&co);
        zre[(b*16 + c)*17 + xc] = fmaf(yr,co,-(yi*s));
        zim[(b*16 + c)*17 + xc] = fmaf(yr,s,  yi*co);
    }
    __syncthreads();

    float t8c[8], t8s[8];
    #pragma unroll
    for(int j=0;j<8;j++){ float s,c; sincosf(sgn*(TWO_PI_F/8.f)*(float)j, &s,&c); t8c[j]=c; t8s[j]=s; }
    int c2 = t>>4; int x2 = t&15;
    float zr_[8], zi_[8];
    #pragma unroll
    for(int bb=0;bb<8;bb++){ zr_[bb]=zre[(bb*16 + c2)*17 + x2]; zi_[bb]=zim[(bb*16 + c2)*17 + x2]; }
    #pragma unroll
    for(int d=0; d<8; d++){
        float Xr=0.f, Xi=0.f;
        #pragma unroll
        for(int bb=0;bb<8;bb++){
            int j=(bb*d)&7;
            Xr = fmaf(zr_[bb], t8c[j], Xr); Xr = fmaf(-zi_[bb], t8s[j], Xr);
            Xi = fmaf(zr_[bb], t8s[j], Xi); Xi = fmaf( zi_[bb], t8c[j], Xi);
        }
        int ky = c2 + 16*d;
        if(REALOUT){
            outr[(size_t)img*N*N + ky*N + x0 + x2] = Xr * (SCALE ? (1.f/128.f) : 1.f);
        } else {
            if(SCALE){ Xr *= (1.f/128.f); Xi *= (1.f/128.f); }
            outc[(size_t)img*N*N + ky*N + x0 + x2] = make_float2(Xr, Xi);
        }
    }
}

// per frequency point (round-8 proven version): Hsum[ik] = sum_p A1T[o][ik,p]*W2T[x][ik,p];
// res1[b,k] = sum_i alpha[b,i]*Hsum[i,k]
__global__ void __launch_bounds__(256) k_res1(const float2* alpha, const float2* A1T,
                                              const float2* W2T, float2* res1){
    __shared__ float2 aval[B*CI];   // 256
    __shared__ float2 hs[IK];       // 1024
    int t = threadIdx.x;
    int f = blockIdx.x;
    int o = f >> 7; int xx = f & (N-1);
    aval[t] = alpha[(size_t)t*(N*N) + o*N + xx];
    const float2* a1 = A1T + (size_t)o*IKP;
    const float2* w2 = W2T + (size_t)xx*IKP;
    #pragma unroll
    for(int nn=0;nn<4;nn++){
        int ik = t + 256*nn;
        float2 h = make_float2(0.f,0.f);
        #pragma unroll
        for(int p=0;p<M1;p++){
            h = cmadd(h, a1[ik*M1+p], w2[ik*M1+p]);
        }
        hs[ik] = h;
    }
    __syncthreads();
    int b = t >> 5; int k = t & 31;
    float2 acc = make_float2(0.f,0.f);
    const float2* av = aval + b*CI;
    #pragma unroll
    for(int i=0;i<CI;i++){
        acc = cmadd(acc, av[i], hs[i*CO + k]);
    }
    res1[((size_t)(b*CO + k))*(N*N) + o*N + xx] = acc;
}

// per (b, i, k-octet, x-half): 256 threads = 32 ol x 4 rg x 2 oh.
// Grid 2048 -> 7 blocks/CU resident (22.5 KB LDS), 28 waves/CU static.
// Thread: o = ol + 32*oi + 64*oh (oi<2), k = k0 + rg + 4*s (s<2), q<5; 4 of 8 x-chunks.
// Partials (oh, xhalf) merge via res2 atomics (S linear in U).
__global__ void __launch_bounds__(256) k_S_res2(const float2* alpha, const float2* A2,
                                                const float2* A1T, const float* wrr,
                                                const float* wri, float2* res2){
    __shared__ float2 tile[128*17];   // alpha chunk [o][xc], stride 17 (2-way banks: free)
    __shared__ float2 A2c[16*40];     // [xc][r], r = kk*5+q (0 conflicts, broadcast reads)
    int t = threadIdx.x;
    int ol = t & 31;
    int rg = (t >> 5) & 3;
    int oh = t >> 7;
    int bid = blockIdx.x;             // ((b*CI + i)*4 + kq)*2 + xh
    int xh = bid & 1;
    int kq = (bid >> 1) & 3;
    int i  = (bid >> 3) & (CI-1);
    int b  = bid >> 8;
    int k0 = kq*8;
    const float2* asrc = alpha + ((size_t)(b*CI + i))*(N*N) + xh*64;

    const int trow = t >> 4, txc = t & 15;   // tile rows trow+16*j (j<8), col txc
    int a2dst[3]; size_t a2src[3]; bool a2ok[3];
    #pragma unroll
    for(int s=0;s<3;s++){
        int e = t + 256*s;                    // 640 = 16*40 total
        a2ok[s] = (e < 640);
        int e2 = a2ok[s] ? e : 0;
        int xcs = e2 / 40, rs = e2 - xcs*40;
        int kk = rs / 5, qq = rs - kk*5;
        a2dst[s] = xcs*40 + rs;
        a2src[s] = ((size_t)(i*CO + k0 + kk)*M2 + qq)*N + xh*64 + xcs;
    }

    float2 U[2][2][5];                        // [s][oi][q]
    #pragma unroll
    for(int s=0;s<2;s++)
        #pragma unroll
        for(int oi=0;oi<2;oi++)
            #pragma unroll
            for(int q=0;q<5;q++) U[s][oi][q] = make_float2(0.f,0.f);

    float2 pre[8], a2pre[3];
    #pragma unroll
    for(int j=0;j<8;j++) pre[j] = asrc[(trow + 16*j)*N + txc];
    #pragma unroll
    for(int s=0;s<3;s++) if(a2ok[s]) a2pre[s] = A2[a2src[s]];

    for(int c=0; c<4; c++){
        __syncthreads();
        #pragma unroll
        for(int j=0;j<8;j++) tile[(trow + 16*j)*17 + txc] = pre[j];
        #pragma unroll
        for(int s=0;s<3;s++) if(a2ok[s]) A2c[a2dst[s]] = a2pre[s];
        if(c < 3){
            int x0n = (c+1)*16;
            #pragma unroll
            for(int j=0;j<8;j++) pre[j] = asrc[(trow + 16*j)*N + x0n + txc];
            #pragma unroll
            for(int s=0;s<3;s++) if(a2ok[s]) a2pre[s] = A2[a2src[s] + x0n];
        }
        __syncthreads();
        #pragma unroll 4
        for(int xc=0; xc<16; xc++){
            float2 a2lo[5], a2hi[5];
            const float2* a2row = A2c + xc*40 + rg*5;
            #pragma unroll
            for(int q=0;q<5;q++){ a2lo[q] = a2row[q]; a2hi[q] = a2row[q+20]; }
            #pragma unroll
            for(int oi=0;oi<2;oi++){
                float2 av = tile[(ol + 32*oi + 64*oh)*17 + xc];
                #pragma unroll
                for(int q=0;q<5;q++){
                    U[0][oi][q] = cmadd(U[0][oi][q], av, a2lo[q]);
                    U[1][oi][q] = cmadd(U[1][oi][q], av, a2hi[q]);
                }
            }
        }
    }

    // S-phase per k-instance: in-register over 2 o's + 32-lane butterfly (per rg half-wave)
    #pragma unroll
    for(int s=0;s<2;s++){
        int k = k0 + rg + 4*s;
        int ik = i*CO + k;
        float2 S[4][5];
        #pragma unroll
        for(int p=0;p<4;p++)
            #pragma unroll
            for(int q=0;q<5;q++) S[p][q] = make_float2(0.f,0.f);
        #pragma unroll
        for(int oi=0;oi<2;oi++){
            int o = ol + 32*oi + 64*oh;
            const float2* a1 = A1T + (size_t)o*IKP + (size_t)ik*M1;
            float2 a1v[4];
            #pragma unroll
            for(int p=0;p<4;p++) a1v[p] = a1[p];
            #pragma unroll
            for(int p=0;p<4;p++)
                #pragma unroll
                for(int q=0;q<5;q++) S[p][q] = cmadd(S[p][q], a1v[p], U[s][oi][q]);
        }
        #pragma unroll
        for(int m=1;m<32;m<<=1){
            #pragma unroll
            for(int p=0;p<4;p++)
                #pragma unroll
                for(int q=0;q<5;q++){
                    S[p][q].x += __shfl_xor(S[p][q].x, m);
                    S[p][q].y += __shfl_xor(S[p][q].y, m);
                }
        }
        if(ol==0){
            const float* wr0 = wrr + ik*(M1*M2);
            const float* wi0 = wri + ik*(M1*M2);
            float2* dst = res2 + (size_t)(b*CO + k)*(M1*M2);
            #pragma unroll
            for(int p=0;p<4;p++)
                #pragma unroll
                for(int q=0;q<5;q++){
                    float2 w = make_float2(wr0[p*5+q], wi0[p*5+q]);
                    float2 v = cmul(w, S[p][q]);
                    atomicAdd(&dst[p*5+q].x, v.x);
                    atomicAdd(&dst[p*5+q].y, v.y);
                }
        }
    }
}

// x2[b,j,y,x] += (1/N^2) * Re( sum_{c,p,q} res2[b,c,p,q]*E1[c,j,p,y]*E2[c,j,q,x] )
__global__ void __launch_bounds__(256) k_x2(const float2* res2, const float2* E1,
                                            const float2* E2, float* out){
    __shared__ float2 Wt[M1][N];
    __shared__ float2 E1s[M1][N];
    int t = threadIdx.x;
    int ys = blockIdx.x & 3;
    int j = (blockIdx.x >> 2) & 31;
    int b = blockIdx.x >> 7;
    int xx = t & (N-1); int hb = t >> 7;
    float acc[16];
    #pragma unroll
    for(int r=0;r<16;r++) acc[r]=0.f;
    for(int c=0;c<CI;c++){
        int ikcj = c*CO + j;
        __syncthreads();
        #pragma unroll
        for(int s=0;s<2;s++){
            int e = t + 256*s;
            int pp = e >> 7; int xi = e & (N-1);
            float2 w = make_float2(0.f,0.f);
            const float2* r2 = res2 + (size_t)(b*CO + c)*(M1*M2) + pp*M2;
            const float2* e2 = E2 + ((size_t)ikcj*M2)*N + xi;
            #pragma unroll
            for(int q=0;q<M2;q++) w = cmadd(w, r2[q], e2[q*N]);
            Wt[pp][xi] = w;
            E1s[pp][xi] = E1[((size_t)ikcj*M1 + pp)*N + xi];
        }
        __syncthreads();
        float2 wreg[M1];
        #pragma unroll
        for(int p=0;p<M1;p++) wreg[p] = Wt[p][xx];
        #pragma unroll
        for(int r=0;r<16;r++){
            int y = 8*r + 2*ys + hb;
            float s = acc[r];
            #pragma unroll
            for(int p=0;p<M1;p++){
                float2 e = E1s[p][y];
                s = fmaf(e.x, wreg[p].x, s); s = fmaf(-e.y, wreg[p].y, s);
            }
            acc[r] = s;
        }
    }
    const float sc = 1.0f/((float)N*(float)N);
    size_t base = (size_t)(b*CO + j)*(N*N);
    #pragma unroll
    for(int r=0;r<16;r++){
        size_t idx = base + (size_t)(8*r + 2*ys + hb)*N + xx;
        out[idx] += acc[r]*sc;
    }
}

extern "C" void kernel_launch(void* const* d_in, const int* in_sizes, int n_in,
                              void* d_out, int out_size, void* d_ws, size_t ws_size,
                              hipStream_t stream){
    const float* x    = (const float*)d_in[0];
    const float* wp1r = (const float*)d_in[1];
    const float* wp1i = (const float*)d_in[2];
    const float* wp2r = (const float*)d_in[3];
    const float* wp2i = (const float*)d_in[4];
    const float* wrr  = (const float*)d_in[5];
    const float* wri  = (const float*)d_in[6];
    const float* ty   = (const float*)d_in[7];
    const float* tx   = (const float*)d_in[8];
    float* out = (float*)d_out;
    float2* ws = (float2*)d_ws;

    const size_t NCIMG = (size_t)B*CI*N*N;        // 4194304 complexes
    float2* bufA  = ws;
    float2* alpha = bufA  + NCIMG;
    float2* res1  = alpha + NCIMG;
    float2* A1T   = res1  + NCIMG;                // N*IKP
    float2* A2    = A1T   + (size_t)N*IKP;        // IKQ*N
    float2* W2T   = A2    + (size_t)IKQ*N;        // N*IKP
    float2* E1    = W2T   + (size_t)N*IKP;        // IKP*N
    float2* E2    = E1    + (size_t)IKP*N;        // IKQ*N
    float2* res2  = E2    + (size_t)IKQ*N;        // B*CO*M1*M2

    k_A1T<<<(N*IKP)/256, 256, 0, stream>>>(wp1r, wp1i, ty, A1T);
    k_E  <<<(IKP*N)/256, 256, 0, stream>>>(wp1r, wp1i, ty, E1);
    k_A2 <<<(IKQ*N)/256, 256, 0, stream>>>(wp2r, wp2i, tx, A2);
    k_E  <<<(IKQ*N)/256, 256, 0, stream>>>(wp2r, wp2i, tx, E2);
    k_W2T<<<(IKP*N)/256, 256, 0, stream>>>(wrr, wri, A2, W2T);

    // forward fft2: rows (real in) then cols
    k_fft_rows<0,1,0><<<(B*CI*N)/16, 256, 0, stream>>>((const void*)x, bufA);
    k_fft_cols<0,0,0><<<B*CI*8, 256, 0, stream>>>(bufA, alpha, nullptr);

    hipMemsetAsync(res2, 0, (size_t)B*CO*M1*M2*sizeof(float2), stream);
    k_res1<<<N*N, 256, 0, stream>>>(alpha, A1T, W2T, res1);
    k_S_res2<<<B*CI*8, 256, 0, stream>>>(alpha, A2, A1T, wrr, wri, res2);

    // inverse fft2: rows (1/N) then cols (real out, 1/N)
    k_fft_rows<1,0,1><<<(B*CO*N)/16, 256, 0, stream>>>((const void*)res1, bufA);
    k_fft_cols<1,1,1><<<B*CO*8, 256, 0, stream>>>(bufA, nullptr, out);
    k_x2<<<B*CO*4, 256, 0, stream>>>(res2, E1, E2, out);
}

// Round 15
// 443.976 us; speedup vs baseline: 1.5367x; 1.5367x over previous
//
#include <hip/hip_runtime.h>
#include <math.h>

#define N 128
#define B 8
#define CI 32
#define CO 32
#define M1 4
#define M2 5
#define IK (CI*CO)       // 1024
#define IKP (IK*M1)      // 4096
#define IKQ (IK*M2)      // 5120
#define TWO_PI_F 6.2831853071795864769f

// 4 v_fma per cmadd, guaranteed
__device__ __forceinline__ float2 cmul(float2 a, float2 b){
    return make_float2(fmaf(a.x,b.x,-(a.y*b.y)), fmaf(a.x,b.y,a.y*b.x));
}
__device__ __forceinline__ float2 cmadd(float2 acc, float2 a, float2 b){
    acc.x = fmaf(a.x, b.x, fmaf(-a.y, b.y, acc.x));
    acc.y = fmaf(a.x, b.y, fmaf( a.y, b.x, acc.y));
    return acc;
}

// A1T[o][ik*M1+p] = 1/(i*2pi*f(o) - wp1[ik,p]); freq-major for contiguous per-o slices
__global__ void k_A1T(const float* wr_, const float* wi_, const float* t_, float2* A1T){
    int idx = blockIdx.x*256 + threadIdx.x;      // [0, N*IKP)
    int o   = idx >> 12;                          // /IKP
    int ikp = idx & (IKP-1);
    float d = t_[1]-t_[0];
    float invnd = 1.0f/((float)N*d);
    int kk = (o < N/2) ? o : o - N;
    float lam = TWO_PI_F * (float)kk * invnd;
    float dr = -wr_[ikp];
    float di = lam - wi_[ikp];
    float inv = 1.0f/(dr*dr + di*di);
    A1T[idx] = make_float2(dr*inv, -di*inv);
}

// A2[ikq][x] natural layout
__global__ void k_A2(const float* wr_, const float* wi_, const float* t_, float2* A2){
    int idx = blockIdx.x*256 + threadIdx.x;      // [0, IKQ*N)
    int ikq = idx >> 7; int xx = idx & (N-1);
    float d = t_[1]-t_[0];
    float invnd = 1.0f/((float)N*d);
    int kk = (xx < N/2) ? xx : xx - N;
    float lam = TWO_PI_F * (float)kk * invnd;
    float dr = -wr_[ikq];
    float di = lam - wi_[ikq];
    float inv = 1.0f/(dr*dr + di*di);
    A2[idx] = make_float2(dr*inv, -di*inv);
}

// E[ikp][y] = exp(wp[ikp] * t[y])
__global__ void k_E(const float* wr_, const float* wi_, const float* t_, float2* E){
    int idx = blockIdx.x*256 + threadIdx.x;
    int ikp = idx >> 7; int y = idx & (N-1);
    float t = t_[y];
    float m = expf(wr_[ikp]*t);
    float s, c; sincosf(wi_[ikp]*t, &s, &c);
    E[idx] = make_float2(m*c, m*s);
}

// W2T[x][ik*M1+p] = sum_q wr[ik,p,q] * A2[ik,q,x]
__global__ void k_W2T(const float* wrr, const float* wri, const float2* A2, float2* W2T){
    int idx = blockIdx.x*256 + threadIdx.x;      // [0, IKP*N)
    int ikp = idx >> 7; int xx = idx & (N-1);
    int ik = ikp >> 2; int p = ikp & 3;
    float2 acc = make_float2(0.f,0.f);
    const float* wr0 = wrr + ik*(M1*M2) + p*M2;
    const float* wi0 = wri + ik*(M1*M2) + p*M2;
    const float2* a2 = A2 + (size_t)ik*(M2*N) + xx;
    #pragma unroll
    for(int q=0;q<M2;q++){
        float2 w = make_float2(wr0[q], wi0[q]);
        acc = cmadd(acc, w, a2[q*N]);
    }
    W2T[(size_t)xx*IKP + ikp] = acc;
}

// ---------- four-step FFT, 128 = 16 x 8 ----------
template<int SIGNPOS, int REALIN, int SCALE>
__global__ void __launch_bounds__(256) k_fft_rows(const void* in_, float2* out){
    const float sgn = SIGNPOS ? 1.0f : -1.0f;
    __shared__ float tre[16*132];
    __shared__ float tim_[16*132];
    __shared__ float zre[16*136];
    __shared__ float zim[16*136];
    int t = threadIdx.x;
    size_t row0 = (size_t)blockIdx.x * 16;

    if(REALIN){
        const float* src = (const float*)in_ + row0*N;
        #pragma unroll
        for(int j=0;j<8;j++){
            int idx = t + 256*j; int r = idx>>7, cl = idx&127;
            tre[r*132+cl] = src[idx];
        }
    } else {
        const float2* src = (const float2*)in_ + row0*N;
        #pragma unroll
        for(int j=0;j<8;j++){
            int idx = t + 256*j; int r = idx>>7, cl = idx&127;
            float2 v = src[idx];
            tre[r*132+cl] = v.x; tim_[r*132+cl] = v.y;
        }
    }
    float t16c[16], t16s[16];
    #pragma unroll
    for(int j=0;j<16;j++){ float s,c; sincosf(sgn*(TWO_PI_F/16.f)*(float)j, &s,&c); t16c[j]=c; t16s[j]=s; }
    __syncthreads();

    int r = t>>4, u = t&15, b = u&7, h = u>>3;
    float xr[16], xi[16];
    #pragma unroll
    for(int a=0;a<16;a++){
        float vr = tre[r*132 + 8*a + b];
        float vi = REALIN ? 0.f : tim_[r*132 + 8*a + b];
        if(h && (a&1)){ vr = -vr; vi = -vi; }
        xr[a]=vr; xi[a]=vi;
    }
    #pragma unroll
    for(int cc=0; cc<8; cc++){
        float yr=0.f, yi=0.f;
        #pragma unroll
        for(int a=0;a<16;a++){
            int j = (a*cc)&15;
            if(REALIN){
                yr = fmaf(xr[a], t16c[j], yr);
                yi = fmaf(xr[a], t16s[j], yi);
            } else {
                yr = fmaf(xr[a], t16c[j], yr); yr = fmaf(-xi[a], t16s[j], yr);
                yi = fmaf(xr[a], t16s[j], yi); yi = fmaf( xi[a], t16c[j], yi);
            }
        }
        int c = 8*h + cc;
        float s,co; sincosf(sgn*(TWO_PI_F/128.f)*(float)(b*c), &s,&co);
        zre[r*136 + b*17 + c] = fmaf(yr,co,-(yi*s));
        zim[r*136 + b*17 + c] = fmaf(yr,s,  yi*co);
    }
    __syncthreads();

    float t8c[8], t8s[8];
    #pragma unroll
    for(int j=0;j<8;j++){ float s,c; sincosf(sgn*(TWO_PI_F/8.f)*(float)j, &s,&c); t8c[j]=c; t8s[j]=s; }
    int r2 = t>>4, c2 = t&15;
    float zr_[8], zi_[8];
    #pragma unroll
    for(int bb=0;bb<8;bb++){ zr_[bb]=zre[r2*136 + bb*17 + c2]; zi_[bb]=zim[r2*136 + bb*17 + c2]; }
    float2* dst = out + (row0 + r2)*N;
    #pragma unroll
    for(int d=0; d<8; d++){
        float Xr=0.f, Xi=0.f;
        #pragma unroll
        for(int bb=0;bb<8;bb++){
            int j=(bb*d)&7;
            Xr = fmaf(zr_[bb], t8c[j], Xr); Xr = fmaf(-zi_[bb], t8s[j], Xr);
            Xi = fmaf(zr_[bb], t8s[j], Xi); Xi = fmaf( zi_[bb], t8c[j], Xi);
        }
        if(SCALE){ Xr *= (1.f/128.f); Xi *= (1.f/128.f); }
        dst[c2 + 16*d] = make_float2(Xr, Xi);
    }
}

template<int SIGNPOS, int REALOUT, int SCALE>
__global__ void __launch_bounds__(256) k_fft_cols(const float2* in, float2* outc, float* outr){
    const float sgn = SIGNPOS ? 1.0f : -1.0f;
    __shared__ float tre[N*17];
    __shared__ float tim_[N*17];
    __shared__ float zre[8*16*17];
    __shared__ float zim[8*16*17];
    int t = threadIdx.x;
    int img = blockIdx.x >> 3; int x0 = (blockIdx.x & 7)*16;
    const float2* src = in + (size_t)img*N*N + x0;
    #pragma unroll
    for(int j=0;j<8;j++){
        int idx = t + 256*j; int y = idx>>4, xc = idx&15;
        float2 v = src[y*N + xc];
        tre[y*17+xc]=v.x; tim_[y*17+xc]=v.y;
    }
    float t16c[16], t16s[16];
    #pragma unroll
    for(int j=0;j<16;j++){ float s,c; sincosf(sgn*(TWO_PI_F/16.f)*(float)j, &s,&c); t16c[j]=c; t16s[j]=s; }
    __syncthreads();

    int xc = t&15, u = t>>4, b = u&7, h = u>>3;
    float xr[16], xi[16];
    #pragma unroll
    for(int a=0;a<16;a++){
        int y = 8*a + b;
        float vr = tre[y*17+xc];
        float vi = tim_[y*17+xc];
        if(h && (a&1)){ vr = -vr; vi = -vi; }
        xr[a]=vr; xi[a]=vi;
    }
    #pragma unroll
    for(int cc=0; cc<8; cc++){
        float yr=0.f, yi=0.f;
        #pragma unroll
        for(int a=0;a<16;a++){
            int j = (a*cc)&15;
            yr = fmaf(xr[a], t16c[j], yr); yr = fmaf(-xi[a], t16s[j], yr);
            yi = fmaf(xr[a], t16s[j], yi); yi = fmaf( xi[a], t16c[j], yi);
        }
        int c = 8*h + cc;
        float s,co; sincosf(sgn*(TWO_PI_F/128.f)*(float)(b*c), &s,&co);
        zre[(b*16 + c)*17 + xc] = fmaf(yr,co,-(yi*s));
        zim[(b*16 + c)*17 + xc] = fmaf(yr,s,  yi*co);
    }
    __syncthreads();

    float t8c[8], t8s[8];
    #pragma unroll
    for(int j=0;j<8;j++){ float s,c; sincosf(sgn*(TWO_PI_F/8.f)*(float)j, &s,&c); t8c[j]=c; t8s[j]=s; }
    int c2 = t>>4; int x2 = t&15;
    float zr_[8], zi_[8];
    #pragma unroll
    for(int bb=0;bb<8;bb++){ zr_[bb]=zre[(bb*16 + c2)*17 + x2]; zi_[bb]=zim[(bb*16 + c2)*17 + x2]; }
    #pragma unroll
    for(int d=0; d<8; d++){
        float Xr=0.f, Xi=0.f;
        #pragma unroll
        for(int bb=0;bb<8;bb++){
            int j=(bb*d)&7;
            Xr = fmaf(zr_[bb], t8c[j], Xr); Xr = fmaf(-zi_[bb], t8s[j], Xr);
            Xi = fmaf(zr_[bb], t8s[j], Xi); Xi = fmaf( zi_[bb], t8c[j], Xi);
        }
        int ky = c2 + 16*d;
        if(REALOUT){
            outr[(size_t)img*N*N + ky*N + x0 + x2] = Xr * (SCALE ? (1.f/128.f) : 1.f);
        } else {
            if(SCALE){ Xr *= (1.f/128.f); Xi *= (1.f/128.f); }
            outc[(size_t)img*N*N + ky*N + x0 + x2] = make_float2(Xr, Xi);
        }
    }
}

// per frequency point (round-8 proven version): Hsum[ik] = sum_p A1T[o][ik,p]*W2T[x][ik,p];
// res1[b,k] = sum_i alpha[b,i]*Hsum[i,k]
__global__ void __launch_bounds__(256) k_res1(const float2* alpha, const float2* A1T,
                                              const float2* W2T, float2* res1){
    __shared__ float2 aval[B*CI];   // 256
    __shared__ float2 hs[IK];       // 1024
    int t = threadIdx.x;
    int f = blockIdx.x;
    int o = f >> 7; int xx = f & (N-1);
    aval[t] = alpha[(size_t)t*(N*N) + o*N + xx];
    const float2* a1 = A1T + (size_t)o*IKP;
    const float2* w2 = W2T + (size_t)xx*IKP;
    #pragma unroll
    for(int nn=0;nn<4;nn++){
        int ik = t + 256*nn;
        float2 h = make_float2(0.f,0.f);
        #pragma unroll
        for(int p=0;p<M1;p++){
            h = cmadd(h, a1[ik*M1+p], w2[ik*M1+p]);
        }
        hs[ik] = h;
    }
    __syncthreads();
    int b = t >> 5; int k = t & 31;
    float2 acc = make_float2(0.f,0.f);
    const float2* av = aval + b*CI;
    #pragma unroll
    for(int i=0;i<CI;i++){
        acc = cmadd(acc, av[i], hs[i*CO + k]);
    }
    res1[((size_t)(b*CO + k))*(N*N) + o*N + xx] = acc;
}

// per (b, i, k-octet): grid 1024 (4 blocks/CU, single generation), 256 threads = 32 ol x 8 kl.
// Thread: k = k0 + kl (1 k), o = ol + 32*oi (oi<4, all 128 o's). Per xc: 9 LDS reads / 20 cmadd
// (was 12/20); butterfly and atomics halved vs round-12 mapping. U = 20 float2 (no VGPR trap).
__global__ void __launch_bounds__(256) k_S_res2(const float2* alpha, const float2* A2,
                                                const float2* A1T, const float* wrr,
                                                const float* wri, float2* res2){
    __shared__ float2 tile[128*17];   // alpha chunk [o][xc], stride 17 (2-way banks: free)
    __shared__ float2 A2c[16*40];     // [xc][r], r = kk*5+q (0 conflicts, broadcast reads)
    int t = threadIdx.x;
    int ol = t & 31;
    int kl = t >> 5;                  // 0..7
    int bid = blockIdx.x;             // (b*CI + i)*4 + kq
    int kq = bid & 3;
    int i  = (bid >> 2) & (CI-1);
    int b  = bid >> 7;
    int k0 = kq*8;
    int k  = k0 + kl;
    int ik = i*CO + k;
    const float2* asrc = alpha + ((size_t)(b*CI + i))*(N*N);

    const int trow = t >> 4, txc = t & 15;   // tile rows trow+16*j (j<8), col txc
    int a2dst[3]; size_t a2src[3]; bool a2ok[3];
    #pragma unroll
    for(int s=0;s<3;s++){
        int e = t + 256*s;                    // 640 = 16*40 total
        a2ok[s] = (e < 640);
        int e2 = a2ok[s] ? e : 0;
        int xcs = e2 / 40, rs = e2 - xcs*40;
        int kk = rs / 5, qq = rs - kk*5;
        a2dst[s] = xcs*40 + rs;
        a2src[s] = ((size_t)(i*CO + k0 + kk)*M2 + qq)*N + xcs;
    }

    float2 U[4][5];                           // [oi][q]
    #pragma unroll
    for(int oi=0;oi<4;oi++)
        #pragma unroll
        for(int q=0;q<5;q++) U[oi][q] = make_float2(0.f,0.f);

    float2 pre[8], a2pre[3];
    #pragma unroll
    for(int j=0;j<8;j++) pre[j] = asrc[(trow + 16*j)*N + txc];
    #pragma unroll
    for(int s=0;s<3;s++) if(a2ok[s]) a2pre[s] = A2[a2src[s]];

    for(int c=0; c<8; c++){
        __syncthreads();
        #pragma unroll
        for(int j=0;j<8;j++) tile[(trow + 16*j)*17 + txc] = pre[j];
        #pragma unroll
        for(int s=0;s<3;s++) if(a2ok[s]) A2c[a2dst[s]] = a2pre[s];
        if(c < 7){
            int x0n = (c+1)*16;
            #pragma unroll
            for(int j=0;j<8;j++) pre[j] = asrc[(trow + 16*j)*N + x0n + txc];
            #pragma unroll
            for(int s=0;s<3;s++) if(a2ok[s]) a2pre[s] = A2[a2src[s] + x0n];
        }
        __syncthreads();
        #pragma unroll 4
        for(int xc=0; xc<16; xc++){
            float2 a2v[5];
            const float2* a2row = A2c + xc*40 + kl*5;
            #pragma unroll
            for(int q=0;q<5;q++) a2v[q] = a2row[q];
            #pragma unroll
            for(int oi=0;oi<4;oi++){
                float2 av = tile[(ol + 32*oi)*17 + xc];
                #pragma unroll
                for(int q=0;q<5;q++) U[oi][q] = cmadd(U[oi][q], av, a2v[q]);
            }
        }
    }

    // S-phase: S[p][q] = sum_o A1[ik,p,o]*U[o][q]; in-register over 4 o's + 32-lane butterfly
    float2 S[4][5];
    #pragma unroll
    for(int p=0;p<4;p++)
        #pragma unroll
        for(int q=0;q<5;q++) S[p][q] = make_float2(0.f,0.f);
    #pragma unroll
    for(int oi=0;oi<4;oi++){
        int o = ol + 32*oi;
        const float2* a1 = A1T + (size_t)o*IKP + (size_t)ik*M1;
        float2 a1v[4];
        #pragma unroll
        for(int p=0;p<4;p++) a1v[p] = a1[p];
        #pragma unroll
        for(int p=0;p<4;p++)
            #pragma unroll
            for(int q=0;q<5;q++) S[p][q] = cmadd(S[p][q], a1v[p], U[oi][q]);
    }
    #pragma unroll
    for(int m=1;m<32;m<<=1){
        #pragma unroll
        for(int p=0;p<4;p++)
            #pragma unroll
            for(int q=0;q<5;q++){
                S[p][q].x += __shfl_xor(S[p][q].x, m);
                S[p][q].y += __shfl_xor(S[p][q].y, m);
            }
    }
    if(ol==0){
        const float* wr0 = wrr + ik*(M1*M2);
        const float* wi0 = wri + ik*(M1*M2);
        float2* dst = res2 + (size_t)(b*CO + k)*(M1*M2);
        #pragma unroll
        for(int p=0;p<4;p++)
            #pragma unroll
            for(int q=0;q<5;q++){
                float2 w = make_float2(wr0[p*5+q], wi0[p*5+q]);
                float2 v = cmul(w, S[p][q]);
                atomicAdd(&dst[p*5+q].x, v.x);
                atomicAdd(&dst[p*5+q].y, v.y);
            }
    }
}

// x2[b,j,y,x] += (1/N^2) * Re( sum_{c,p,q} res2[b,c,p,q]*E1[c,j,p,y]*E2[c,j,q,x] )
__global__ void __launch_bounds__(256) k_x2(const float2* res2, const float2* E1,
                                            const float2* E2, float* out){
    __shared__ float2 Wt[M1][N];
    __shared__ float2 E1s[M1][N];
    int t = threadIdx.x;
    int ys = blockIdx.x & 3;
    int j = (blockIdx.x >> 2) & 31;
    int b = blockIdx.x >> 7;
    int xx = t & (N-1); int hb = t >> 7;
    float acc[16];
    #pragma unroll
    for(int r=0;r<16;r++) acc[r]=0.f;
    for(int c=0;c<CI;c++){
        int ikcj = c*CO + j;
        __syncthreads();
        #pragma unroll
        for(int s=0;s<2;s++){
            int e = t + 256*s;
            int pp = e >> 7; int xi = e & (N-1);
            float2 w = make_float2(0.f,0.f);
            const float2* r2 = res2 + (size_t)(b*CO + c)*(M1*M2) + pp*M2;
            const float2* e2 = E2 + ((size_t)ikcj*M2)*N + xi;
            #pragma unroll
            for(int q=0;q<M2;q++) w = cmadd(w, r2[q], e2[q*N]);
            Wt[pp][xi] = w;
            E1s[pp][xi] = E1[((size_t)ikcj*M1 + pp)*N + xi];
        }
        __syncthreads();
        float2 wreg[M1];
        #pragma unroll
        for(int p=0;p<M1;p++) wreg[p] = Wt[p][xx];
        #pragma unroll
        for(int r=0;r<16;r++){
            int y = 8*r + 2*ys + hb;
            float s = acc[r];
            #pragma unroll
            for(int p=0;p<M1;p++){
                float2 e = E1s[p][y];
                s = fmaf(e.x, wreg[p].x, s); s = fmaf(-e.y, wreg[p].y, s);
            }
            acc[r] = s;
        }
    }
    const float sc = 1.0f/((float)N*(float)N);
    size_t base = (size_t)(b*CO + j)*(N*N);
    #pragma unroll
    for(int r=0;r<16;r++){
        size_t idx = base + (size_t)(8*r + 2*ys + hb)*N + xx;
        out[idx] += acc[r]*sc;
    }
}

extern "C" void kernel_launch(void* const* d_in, const int* in_sizes, int n_in,
                              void* d_out, int out_size, void* d_ws, size_t ws_size,
                              hipStream_t stream){
    const float* x    = (const float*)d_in[0];
    const float* wp1r = (const float*)d_in[1];
    const float* wp1i = (const float*)d_in[2];
    const float* wp2r = (const float*)d_in[3];
    const float* wp2i = (const float*)d_in[4];
    const float* wrr  = (const float*)d_in[5];
    const float* wri  = (const float*)d_in[6];
    const float* ty   = (const float*)d_in[7];
    const float* tx   = (const float*)d_in[8];
    float* out = (float*)d_out;
    float2* ws = (float2*)d_ws;

    const size_t NCIMG = (size_t)B*CI*N*N;        // 4194304 complexes
    float2* bufA  = ws;
    float2* alpha = bufA  + NCIMG;
    float2* res1  = alpha + NCIMG;
    float2* A1T   = res1  + NCIMG;                // N*IKP
    float2* A2    = A1T   + (size_t)N*IKP;        // IKQ*N
    float2* W2T   = A2    + (size_t)IKQ*N;        // N*IKP
    float2* E1    = W2T   + (size_t)N*IKP;        // IKP*N
    float2* E2    = E1    + (size_t)IKP*N;        // IKQ*N
    float2* res2  = E2    + (size_t)IKQ*N;        // B*CO*M1*M2

    k_A1T<<<(N*IKP)/256, 256, 0, stream>>>(wp1r, wp1i, ty, A1T);
    k_E  <<<(IKP*N)/256, 256, 0, stream>>>(wp1r, wp1i, ty, E1);
    k_A2 <<<(IKQ*N)/256, 256, 0, stream>>>(wp2r, wp2i, tx, A2);
    k_E  <<<(IKQ*N)/256, 256, 0, stream>>>(wp2r, wp2i, tx, E2);
    k_W2T<<<(IKP*N)/256, 256, 0, stream>>>(wrr, wri, A2, W2T);

    // forward fft2: rows (real in) then cols
    k_fft_rows<0,1,0><<<(B*CI*N)/16, 256, 0, stream>>>((const void*)x, bufA);
    k_fft_cols<0,0,0><<<B*CI*8, 256, 0, stream>>>(bufA, alpha, nullptr);

    hipMemsetAsync(res2, 0, (size_t)B*CO*M1*M2*sizeof(float2), stream);
    k_res1<<<N*N, 256, 0, stream>>>(alpha, A1T, W2T, res1);
    k_S_res2<<<B*CI*4, 256, 0, stream>>>(alpha, A2, A1T, wrr, wri, res2);

    // inverse fft2: rows (1/N) then cols (real out, 1/N)
    k_fft_rows<1,0,1><<<(B*CO*N)/16, 256, 0, stream>>>((const void*)res1, bufA);
    k_fft_cols<1,1,1><<<B*CO*8, 256, 0, stream>>>(bufA, nullptr, out);
    k_x2<<<B*CO*4, 256, 0, stream>>>(res2, E1, E2, out);
}